// Round 9
// baseline (112.849 us; speedup 1.0000x reference)
//
#include <hip/hip_runtime.h>

#define NV 13824   // 24*24*24 voxels per batch
#define CCH 64     // channels
#define NB 2       // batch

// ---------------------------------------------------------------------------
// Kernel 1 (v6): q/k/v projections, occupancy-first design.
// Thread = (voxel, channel-quad): computes q/k/v[c0..c0+3] for one voxel
// (12 outputs, 768 FMA). x row (64 floats) in registers via 64 dense
// lane-coalesced loads; W rows are wave-uniform -> readfirstlane -> s_load.
// No LDS in the compute path. 1728 blocks x 4 waves = 6912 waves (6.75/SIMD;
// v1-v5 ran 0.8-1.7/SIMD and were latency-bound at ~38us with VALUBusy 26%).
// Store through a padded LDS bounce sb[3][64][20] -> 64B-per-voxel dense
// stores (full sectors). XCD chunking (1728 = 8*216) aligns each XCD's
// voxel range with attn's chunks.
// ---------------------------------------------------------------------------
__global__ __launch_bounds__(256) void qkv_kernel(
    const float* __restrict__ x,
    const float* __restrict__ Wq, const float* __restrict__ bq,
    const float* __restrict__ Wk, const float* __restrict__ bk,
    const float* __restrict__ Wv, const float* __restrict__ bv,
    float* __restrict__ qo, float* __restrict__ ko, float* __restrict__ vo)
{
    __shared__ float sb[3][64][20];   // padded: stride 20 (odd*4) -> no conflicts

    const int t    = threadIdx.x;
    const int bid  = blockIdx.x;
    const int lb   = (bid & 7) * 216 + (bid >> 3);  // bijective XCD chunking
    const int tile = lb >> 2;         // voxel tile 0..431
    const int cqg  = lb & 3;          // channel-quad group 0..3
    const int wid  = t >> 6;          // wave 0..3 (uniform)
    const int lane = t & 63;

    const int gr0 = tile * 64;        // global row base (64 | NV: no straddle)
    const int b   = gr0 / NV;
    const int nn  = gr0 - b * NV;
    const int n   = nn + lane;        // this thread's voxel (within batch)
    // wave-uniform channel base, forced into SGPR
    const int c0  = __builtin_amdgcn_readfirstlane(cqg * 16 + wid * 4);

    const float* xb = x + (size_t)b * CCH * NV + n;

    // 64 independent dense loads: lanes = consecutive n -> 256B per instr
    float xr[64];
    #pragma unroll
    for (int k = 0; k < 64; ++k) xr[k] = xb[(size_t)k * NV];

    const float* const Ws[3] = {Wq, Wk, Wv};
    const float* const bs[3] = {bq, bk, bv};

    // 12 outputs; W reads are SGPR-offset float4 (s_load), fully unrolled
    #pragma unroll
    for (int m = 0; m < 3; ++m) {
        const float sc = (m == 0) ? 0.25f : 1.0f;   // fold hd^-0.5 into q
        #pragma unroll
        for (int j = 0; j < 4; ++j) {
            const float* row = Ws[m] + (size_t)(c0 + j) * 64;
            float a = bs[m][c0 + j];
            #pragma unroll
            for (int k4 = 0; k4 < 16; ++k4) {
                const float4 wv = *(const float4*)(row + k4 * 4);
                a += xr[k4 * 4 + 0] * wv.x + xr[k4 * 4 + 1] * wv.y
                   + xr[k4 * 4 + 2] * wv.z + xr[k4 * 4 + 3] * wv.w;
            }
            sb[m][lane][wid * 4 + j] = a * sc;   // stride-20 rows: conflict-free
        }
    }
    __syncthreads();

    // dense store: 4 lanes cover one voxel's 64B slice; full 32B sectors
    const int v = t >> 2;             // voxel 0..63
    const int i = t & 3;              // float4 within 16-channel slice
    float* const outs[3] = {qo, ko, vo};
    #pragma unroll
    for (int m = 0; m < 3; ++m) {
        const float4 o4 = *(const float4*)(&sb[m][v][i * 4]);
        *(float4*)(outs[m] + (size_t)(gr0 + v) * 64 + cqg * 16 + i * 4) = o4;
    }
}

// ---------------------------------------------------------------------------
// Kernel 2 (v4, unchanged): local attention.
// Gather map: 8 lanes = one voxel's full 256B k/v row -> coalesced gathers.
// Branch-free taps (clamp + 0/1 mask) preserve zero-padded-k semantics.
// Dense I/O via padded LDS transpose so[32][65].
// ---------------------------------------------------------------------------
__global__ __launch_bounds__(256) void attn_kernel(
    const float* __restrict__ x,
    const float* __restrict__ qw,
    const float* __restrict__ kw,
    const float* __restrict__ vw,
    float* __restrict__ out)
{
    __shared__ float so[32][65];   // padded: conflict-free

    const int t    = threadIdx.x;
    const int bid  = blockIdx.x;
    const int lb   = (bid & 7) * 108 + (bid >> 3);   // bijective XCD chunking
    const int half = t & 1;
    const int head = (t >> 1) & 3;
    const int vb   = t >> 3;             // 0..31
    const int n0g  = lb * 32;            // 32 | NV -> no batch straddle
    const int gr   = n0g + vb;
    const int b    = gr / NV;
    const int n    = gr - b * NV;
    const int d    = n / 576;
    const int rem  = n - d * 576;
    const int r    = rem / 24;
    const int w    = rem - r * 24;
    const int coff = head * 16 + half * 8;

    // branch-free neighbor table: clamped index + 0/1 mask
    int   idx[27];
    float msk[27];
    #pragma unroll
    for (int i3 = 0; i3 < 3; ++i3)
    #pragma unroll
    for (int j3 = 0; j3 < 3; ++j3)
    #pragma unroll
    for (int l3 = 0; l3 < 3; ++l3) {
        const int dd = d + i3 - 1;
        const int rr = r + j3 - 1;
        const int ww = w + l3 - 1;
        const bool ok = ((unsigned)dd < 24u) & ((unsigned)rr < 24u) & ((unsigned)ww < 24u);
        const int jj = (i3 * 3 + j3) * 3 + l3;
        idx[jj] = ok ? ((dd * 24 + rr) * 24 + ww) : n;
        msk[jj] = ok ? 1.f : 0.f;
    }

    // q fragment (8 floats, already scaled by 0.25 in qkv)
    const float4* qp = (const float4*)(qw + (size_t)gr * 64 + coff);
    const float4 q0 = qp[0], q1 = qp[1];

    const float* kbase = kw + (size_t)b * NV * 64 + coff;

    // unconditional masked dot per tap
    float logit[27];
    #pragma unroll
    for (int j = 0; j < 27; ++j) {
        const float4* kp = (const float4*)(kbase + (size_t)idx[j] * 64);
        const float4 k0 = kp[0], k1 = kp[1];
        float a;
        a  = q0.x * k0.x + q0.y * k0.y + q0.z * k0.z + q0.w * k0.w;
        a += q1.x * k1.x + q1.y * k1.y + q1.z * k1.z + q1.w * k1.w;
        logit[j] = a * msk[j];
    }
    #pragma unroll
    for (int j = 0; j < 27; ++j)
        logit[j] += __shfl_xor(logit[j], 1, 64);   // combine 8+8 dim halves

    float ssum = 0.f;
    #pragma unroll
    for (int j = 0; j < 27; ++j) {
        const float e = __expf(logit[j]);   // OOB: exp(0)=1 participates
        logit[j] = e;
        ssum += e;
    }
    const float inv = 1.f / ssum;

    float a0=0.f,a1=0.f,a2=0.f,a3=0.f,a4=0.f,a5=0.f,a6=0.f,a7=0.f;
    const float* vbase = vw + (size_t)b * NV * 64 + coff;
    #pragma unroll
    for (int j = 0; j < 27; ++j) {
        const float p = logit[j] * msk[j];   // OOB contributes v = 0
        const float4* vp = (const float4*)(vbase + (size_t)idx[j] * 64);
        const float4 v0 = vp[0], v1 = vp[1];
        a0 += p * v0.x; a1 += p * v0.y; a2 += p * v0.z; a3 += p * v0.w;
        a4 += p * v1.x; a5 += p * v1.y; a6 += p * v1.z; a7 += p * v1.w;
    }

    // LDS transpose: each lane deposits its 8 channels (scaled by inv)
    so[vb][coff + 0] = a0 * inv;  so[vb][coff + 1] = a1 * inv;
    so[vb][coff + 2] = a2 * inv;  so[vb][coff + 3] = a3 * inv;
    so[vb][coff + 4] = a4 * inv;  so[vb][coff + 5] = a5 * inv;
    so[vb][coff + 6] = a6 * inv;  so[vb][coff + 7] = a7 * inv;
    __syncthreads();

    // dense store phase: lanes = 32 consecutive voxels, 8 channels each
    const int vv = t & 31;
    const int cg = t >> 5;
    const int bs = n0g / NV;
    const int nb0 = n0g - bs * NV;
    const float* xb = x   + (size_t)bs * CCH * NV + nb0 + vv;
    float*       ob = out + (size_t)bs * CCH * NV + nb0 + vv;
    #pragma unroll
    for (int i = 0; i < 8; ++i) {
        const int c = cg * 8 + i;
        ob[(size_t)c * NV] = xb[(size_t)c * NV] + so[vv][c];
    }
}

// ---------------------------------------------------------------------------
extern "C" void kernel_launch(void* const* d_in, const int* in_sizes, int n_in,
                              void* d_out, int out_size, void* d_ws, size_t ws_size,
                              hipStream_t stream) {
    const float* x  = (const float*)d_in[0];
    // d_in[1] = cemb, unused by the reference forward
    const float* Wq = (const float*)d_in[2];
    const float* bq = (const float*)d_in[3];
    const float* Wk = (const float*)d_in[4];
    const float* bk = (const float*)d_in[5];
    const float* Wv = (const float*)d_in[6];
    const float* bv = (const float*)d_in[7];
    float* out = (float*)d_out;

    float* ws = (float*)d_ws;
    const size_t RC = (size_t)NB * NV * CCH;   // 1,769,472 floats per tensor
    float* q = ws;
    float* k = ws + RC;
    float* v = ws + 2 * RC;

    const int nrows = NB * NV;                  // 27648

    qkv_kernel<<<nrows / 16, 256, 0, stream>>>(x, Wq, bq, Wk, bk, Wv, bv, q, k, v);
    attn_kernel<<<nrows / 32, 256, 0, stream>>>(x, q, k, v, out);
}